// Round 1
// baseline (10038.497 us; speedup 1.0000x reference)
//
#include <hip/hip_runtime.h>
#include <stdint.h>

// BiLSTM: B=64, T=512, D=512, U=512. Two independent forward-scanned LSTMs.
// Phase 0: convert inputs/weights to fp16 (weights transposed to [n][k]).
// Phase 1: xz = x @ W + b  (MFMA fp16 GEMM, per time-chunk)
// Phase 2: persistent cooperative recurrence: z = xz + h @ U, gates, h/c update.

typedef _Float16 f16;
typedef _Float16 f16x8 __attribute__((ext_vector_type(8)));
typedef _Float16 f16x4 __attribute__((ext_vector_type(4)));
typedef float    f32x4 __attribute__((ext_vector_type(4)));

typedef __attribute__((address_space(1))) const void* gas_ptr;
typedef __attribute__((address_space(3))) void* las_ptr;

__device__ inline void gl_lds16(const void* g, void* l) {
    __builtin_amdgcn_global_load_lds((gas_ptr)g, (las_ptr)l, 16, 0, 0);
}

// agent-coherent 16B load/store as 4 relaxed dword atomics (bypass stale L1/L2,
// hit the coherence point = IF$; avoids threadfence wbl2/inv on the hot path)
__device__ inline f16x8 aload16(const f16* p) {
    union { unsigned u[4]; f16x8 v; } t;
    const unsigned* q = (const unsigned*)p;
#pragma unroll
    for (int i = 0; i < 4; ++i)
        t.u[i] = __hip_atomic_load(q + i, __ATOMIC_RELAXED, __HIP_MEMORY_SCOPE_AGENT);
    return t.v;
}
__device__ inline void astore16(f16* p, f16x8 v) {
    union { unsigned u[4]; f16x8 v8; } t; t.v8 = v;
    unsigned* q = (unsigned*)p;
#pragma unroll
    for (int i = 0; i < 4; ++i)
        __hip_atomic_store(q + i, t.u[i], __ATOMIC_RELAXED, __HIP_MEMORY_SCOPE_AGENT);
}

// ---------------- conversion kernels ----------------

__global__ void k_cvt(const float* __restrict__ src, f16* __restrict__ dst, int n8) {
    int i = blockIdx.x * 256 + threadIdx.x;
    if (i >= n8) return;
    const float4* s = (const float4*)src;
    float4 a = s[2 * i], b = s[2 * i + 1];
    f16x8 o = {(f16)a.x, (f16)a.y, (f16)a.z, (f16)a.w,
               (f16)b.x, (f16)b.y, (f16)b.z, (f16)b.w};
    *(f16x8*)(dst + 8 * (size_t)i) = o;
}

// src [512][2048] f32 -> dst [2048][512] f16 (transpose)
__global__ void k_tcvt(const float* __restrict__ src, f16* __restrict__ dst) {
    int tid = blockIdx.x * 256 + threadIdx.x;   // 131072 total
    int kc = tid >> 11;          // 0..63  (k chunk of 8)
    int n  = tid & 2047;
    f16x8 o;
#pragma unroll
    for (int j = 0; j < 8; ++j)
        o[j] = (f16)src[(size_t)(kc * 8 + j) * 2048 + n];
    *(f16x8*)(dst + (size_t)n * 512 + kc * 8) = o;
}

// ---------------- projection GEMM ----------------
// xz[d][b][tc][n] (fp16) = x16[d][b][t0+tc][:] @ WT[d][n][:] + bias[n]
// BM=128, BN=128, BK=32, 256 threads (4 waves 2x2), m97-style single-sync loop.

__global__ __launch_bounds__(256) void k_proj(
    const f16* __restrict__ x16, const f16* __restrict__ WT,
    const float* __restrict__ bfw, const float* __restrict__ bbw,
    f16* __restrict__ xz, int t0, int CT, int lct) {
    __shared__ f16 smem[16384];          // A: [0,8192)x2buf=16KB via halves; B: +8192
    f16* As = smem;                      // As[buf*4096 + ...]
    f16* Bs = smem + 8192;

    const int tid = threadIdx.x;
    const int l = tid & 63, v = tid >> 6;
    const int mt = blockIdx.x, nt = blockIdx.y, d = blockIdx.z;
    const int wm = v >> 1, wn = v & 1;
    const int lr4 = l >> 4, c16 = l & 15;

    f32x4 acc[4][4];
#pragma unroll
    for (int i = 0; i < 4; ++i)
#pragma unroll
        for (int j = 0; j < 4; ++j) acc[i][j] = (f32x4)0.f;

    auto stage = [&](int kk, int buf) {
#pragma unroll
        for (int rd = 0; rd < 2; ++rd) {
            int idx = rd * 256 + tid;
            int r = idx >> 2, kp = idx & 3;
            int m = mt * 128 + r;
            int b = m >> lct, tc = m & (CT - 1);
            const f16* ga = x16 + (((size_t)(d * 64 + b) * 512 + (t0 + tc)) * 512 + kk * 32 + kp * 8);
            gl_lds16(ga, &As[buf * 4096 + (rd * 256 + v * 64) * 8]);
        }
#pragma unroll
        for (int rd = 0; rd < 2; ++rd) {
            int idx = rd * 256 + tid;
            int r = idx >> 2, kp = idx & 3;
            const f16* gb = WT + ((size_t)(d * 2048 + nt * 128 + r) * 512 + kk * 32 + kp * 8);
            gl_lds16(gb, &Bs[buf * 4096 + (rd * 256 + v * 64) * 8]);
        }
    };

    stage(0, 0);
    for (int kk = 0; kk < 16; ++kk) {
        __syncthreads();                          // drains vmcnt for staged buf
        if (kk < 15) stage(kk + 1, (kk + 1) & 1);
        int buf = kk & 1;
        f16x8 af[4], bfr[4];
#pragma unroll
        for (int mf = 0; mf < 4; ++mf)
            af[mf] = *(const f16x8*)&As[buf * 4096 + (wm * 64 + mf * 16 + c16) * 32 + lr4 * 8];
#pragma unroll
        for (int nf = 0; nf < 4; ++nf)
            bfr[nf] = *(const f16x8*)&Bs[buf * 4096 + (wn * 64 + nf * 16 + c16) * 32 + lr4 * 8];
#pragma unroll
        for (int mf = 0; mf < 4; ++mf)
#pragma unroll
            for (int nf = 0; nf < 4; ++nf)
                acc[mf][nf] = __builtin_amdgcn_mfma_f32_16x16x32_f16(af[mf], bfr[nf], acc[mf][nf], 0, 0, 0);
    }
    __syncthreads();

    const float* bias = d ? bbw : bfw;
    float bv[4];
#pragma unroll
    for (int nf = 0; nf < 4; ++nf) bv[nf] = bias[nt * 128 + wn * 64 + nf * 16 + c16];

    // stage C tile to LDS (fp16), then coalesced 16B writes
    f16* Cs = smem;
#pragma unroll
    for (int mf = 0; mf < 4; ++mf)
#pragma unroll
        for (int nf = 0; nf < 4; ++nf)
#pragma unroll
            for (int r = 0; r < 4; ++r) {
                int row = wm * 64 + mf * 16 + lr4 * 4 + r;
                int col = wn * 64 + nf * 16 + c16;
                Cs[row * 128 + col] = (f16)(acc[mf][nf][r] + bv[nf]);
            }
    __syncthreads();
#pragma unroll
    for (int ch = 0; ch < 8; ++ch) {
        int flat = ch * 256 + tid;
        int row = flat >> 4, cc = flat & 15;
        int m = mt * 128 + row;
        int b = m >> lct, tc = m & (CT - 1);
        f16x8 val = *(const f16x8*)&Cs[row * 128 + cc * 8];
        *(f16x8*)&xz[((size_t)(d * 64 + b) * CT + tc) * 2048 + nt * 128 + cc * 8] = val;
    }
}

// ---------------- persistent recurrence ----------------
// 128 blocks x 256 thr: block = (dir d, batch-group grp of 16 rows, unit-WG wg of 32 units).
// U frags resident in VGPRs. Per step: spin on group counter, z = xz + h@U (MFMA),
// gates via shfl_xor (cols permuted unit*4+gate), h -> agent-scope stores, +1 arrive.

__global__ __launch_bounds__(256, 1) void k_recur(
    const f16* __restrict__ xz, const f16* __restrict__ UT,
    f16* __restrict__ hbuf, float* __restrict__ cbuf,
    unsigned* __restrict__ cnt, float* __restrict__ out,
    int t0, int CT) {
    __shared__ f16 xzsm[2][2048];
    __shared__ f16 wsm[4][128];

    const int tid = threadIdx.x;
    const int l = tid & 63, v = tid >> 6;
    const int bx = blockIdx.x;
    const int d   = bx >> 6;
    const int grp = (bx >> 4) & 3;
    const int wg  = bx & 15;
    const int wu0 = wg * 32;
    const int lr4 = l >> 4;          // 0..3
    const int du  = (l & 15) >> 2;   // 0..3
    const int gid = l & 3;           // gate: 0=i 1=f 2=g 3=o
    const int gidx = d * 4 + grp;

    int unitloc[2], nstd[2];
#pragma unroll
    for (int nf = 0; nf < 2; ++nf) {
        int u = wu0 + v * 8 + nf * 4 + du;
        unitloc[nf] = v * 8 + nf * 4 + du;
        nstd[nf] = gid * 512 + u;
    }

    // resident U fragments: 2 n-frags x 16 k-frags, 128 VGPR
    f16x8 Ufr[2][16];
#pragma unroll
    for (int nf = 0; nf < 2; ++nf)
#pragma unroll
        for (int kk = 0; kk < 16; ++kk)
            Ufr[nf][kk] = *(const f16x8*)&UT[((size_t)d * 2048 + nstd[nf]) * 512 + kk * 32 + lr4 * 8];

    // c state (redundant across the 4 gate lanes)
    float cst[2][4];
#pragma unroll
    for (int nf = 0; nf < 2; ++nf)
#pragma unroll
        for (int r = 0; r < 4; ++r)
            cst[nf][r] = cbuf[((size_t)d * 64 + grp * 16 + lr4 * 4 + r) * 512 + (wu0 + v * 8 + nf * 4 + du)];

    // stage xz for tl=0
    {
        int row = tid >> 4, gate = (tid >> 2) & 3, u8 = tid & 3;
        const f16* g = xz + (((size_t)(d * 64 + grp * 16 + row) * CT + 0) * 2048 + gate * 512 + wu0 + u8 * 8);
        gl_lds16(g, &xzsm[0][v * 512]);
    }

    const size_t hstride = 16 * 512;
    f16* hb = hbuf + (size_t)(d * 4 + grp) * 2 * hstride;

    for (int tl = 0; tl < CT; ++tl) {
        const int gt = t0 + tl;
        __syncthreads();   // xzsm[tl&1] staged (vmcnt drained); wsm reusable

        // z init from xz
        f32x4 acc0, acc1;
#pragma unroll
        for (int r = 0; r < 4; ++r) {
            acc0[r] = (float)xzsm[tl & 1][((lr4 * 4 + r) * 4 + gid) * 32 + unitloc[0]];
            acc1[r] = (float)xzsm[tl & 1][((lr4 * 4 + r) * 4 + gid) * 32 + unitloc[1]];
        }

        // prefetch next xz (independent of h; overlaps the spin)
        if (tl + 1 < CT) {
            int row = tid >> 4, gate = (tid >> 2) & 3, u8 = tid & 3;
            const f16* g = xz + (((size_t)(d * 64 + grp * 16 + row) * CT + (tl + 1)) * 2048 + gate * 512 + wu0 + u8 * 8);
            gl_lds16(g, &xzsm[(tl + 1) & 1][v * 512]);
        }

        // wait for h_{gt} from all 16 WGs of the group
        if (gt > 0) {
            unsigned target = 16u * (unsigned)gt;
            while (__hip_atomic_load(cnt + gidx, __ATOMIC_RELAXED, __HIP_MEMORY_SCOPE_AGENT) < target)
                __builtin_amdgcn_s_sleep(1);
        }
        asm volatile("" ::: "memory");

        // z += h @ U
        const f16* hsrc = hb + (size_t)(gt & 1) * hstride + (size_t)(l & 15) * 512 + lr4 * 8;
#pragma unroll
        for (int kh = 0; kh < 2; ++kh) {
            f16x8 af[8];
#pragma unroll
            for (int j = 0; j < 8; ++j) af[j] = aload16(hsrc + (kh * 8 + j) * 32);
#pragma unroll
            for (int j = 0; j < 8; ++j) {
                acc0 = __builtin_amdgcn_mfma_f32_16x16x32_f16(af[j], Ufr[0][kh * 8 + j], acc0, 0, 0, 0);
                acc1 = __builtin_amdgcn_mfma_f32_16x16x32_f16(af[j], Ufr[1][kh * 8 + j], acc1, 0, 0, 0);
            }
        }

        // own-gate activation (gate 2 = tanh, else sigmoid)
        float act[2][4];
#pragma unroll
        for (int nf = 0; nf < 2; ++nf)
#pragma unroll
            for (int r = 0; r < 4; ++r) {
                float z = nf ? acc1[r] : acc0[r];
                float zz = (gid == 2) ? 2.f * z : z;
                float r0 = 1.f / (1.f + __expf(-zz));
                act[nf][r] = (gid == 2) ? 2.f * r0 - 1.f : r0;
            }

        // exchange gates among the 4 adjacent lanes; update c; gate0 computes h
#pragma unroll
        for (int nf = 0; nf < 2; ++nf)
#pragma unroll
            for (int r = 0; r < 4; ++r) {
                float a0 = act[nf][r];
                float a1 = __shfl_xor(a0, 1);
                float a2 = __shfl_xor(a0, 2);
                float a3 = __shfl_xor(a0, 3);
                int mi = gid, mf_ = gid ^ 1, mg = gid ^ 2, mo = gid ^ 3;
                float iv = mi == 0 ? a0 : mi == 1 ? a1 : mi == 2 ? a2 : a3;
                float fv = mf_ == 0 ? a0 : mf_ == 1 ? a1 : mf_ == 2 ? a2 : a3;
                float gv = mg == 0 ? a0 : mg == 1 ? a1 : mg == 2 ? a2 : a3;
                float ov = mo == 0 ? a0 : mo == 1 ? a1 : mo == 2 ? a2 : a3;
                float cn = fv * cst[nf][r] + iv * gv;
                cst[nf][r] = cn;
                if (gid == 0) {
                    float th = copysignf(1.f - 2.f / (__expf(2.f * fabsf(cn)) + 1.f), cn);
                    wsm[v][(nf * 4 + du) * 16 + lr4 * 4 + r] = (f16)(ov * th);
                }
            }

        // lanes 0..15 of each wave gather their batch-row, store h + output
        if (l < 16) {
            f16x8 hv8;
            float ha[8];
#pragma unroll
            for (int j = 0; j < 8; ++j) { f16 h = wsm[v][j * 16 + l]; hv8[j] = h; ha[j] = (float)h; }
            astore16(hb + (size_t)((gt + 1) & 1) * hstride + (size_t)l * 512 + wu0 + v * 8, hv8);
            size_t ob = ((size_t)(grp * 16 + l) * 512 + gt) * 1024 + d * 512 + wu0 + v * 8;
            float4 o0 = {ha[0], ha[1], ha[2], ha[3]};
            float4 o1 = {ha[4], ha[5], ha[6], ha[7]};
            *(float4*)&out[ob] = o0;
            *(float4*)&out[ob + 4] = o1;
        }
        __syncthreads();   // all lanes' h stores drained (vmcnt) before arrive
        if (tid == 0)
            __hip_atomic_fetch_add(cnt + gidx, 1u, __ATOMIC_RELEASE, __HIP_MEMORY_SCOPE_AGENT);
    }

    // persist c for next chunk
    if (gid == 0) {
#pragma unroll
        for (int nf = 0; nf < 2; ++nf)
#pragma unroll
            for (int r = 0; r < 4; ++r)
                cbuf[((size_t)d * 64 + grp * 16 + lr4 * 4 + r) * 512 + (wu0 + v * 8 + nf * 4 + du)] = cst[nf][r];
    }
}

// ---------------- host ----------------

extern "C" void kernel_launch(void* const* d_in, const int* in_sizes, int n_in,
                              void* d_out, int out_size, void* d_ws, size_t ws_size,
                              hipStream_t stream) {
    const float* xf = (const float*)d_in[0];
    const float* xb = (const float*)d_in[1];
    const float* Wf = (const float*)d_in[2];
    const float* Uf = (const float*)d_in[3];
    const float* bf = (const float*)d_in[4];
    const float* Wb = (const float*)d_in[5];
    const float* Ub = (const float*)d_in[6];
    const float* bb = (const float*)d_in[7];
    float* out = (float*)d_out;

    char* ws = (char*)d_ws;
    size_t off = 0;
    auto alloc = [&](size_t bytes) { size_t o = off; off = (off + bytes + 255) & ~(size_t)255; return o; };
    size_t o_x16 = alloc((size_t)2 * 64 * 512 * 512 * 2);
    size_t o_wt  = alloc((size_t)2 * 2048 * 512 * 2);
    size_t o_ut  = alloc((size_t)2 * 2048 * 512 * 2);
    size_t o_hb  = alloc((size_t)2 * 4 * 2 * 16 * 512 * 2);
    size_t o_cb  = alloc((size_t)2 * 64 * 512 * 4);
    size_t o_cnt = alloc(256);
    size_t fixed = off;
    int CT = 512;
    while (CT > 32 && fixed + (size_t)2 * 64 * CT * 2048 * 2 > ws_size) CT >>= 1;
    size_t o_xz = alloc((size_t)2 * 64 * CT * 2048 * 2);
    int lct = (CT == 512) ? 9 : (CT == 256) ? 8 : (CT == 128) ? 7 : (CT == 64) ? 6 : 5;

    f16* x16 = (f16*)(ws + o_x16);
    f16* wt16 = (f16*)(ws + o_wt);
    f16* ut16 = (f16*)(ws + o_ut);
    f16* hb   = (f16*)(ws + o_hb);
    float* cb = (float*)(ws + o_cb);
    unsigned* cp = (unsigned*)(ws + o_cnt);
    f16* xzp  = (f16*)(ws + o_xz);

    const int n8 = 16777216 / 8;   // per x tensor
    k_cvt<<<8192, 256, 0, stream>>>(xf, x16, n8);
    k_cvt<<<8192, 256, 0, stream>>>(xb, x16 + (size_t)16777216, n8);
    k_tcvt<<<512, 256, 0, stream>>>(Wf, wt16);
    k_tcvt<<<512, 256, 0, stream>>>(Wb, wt16 + (size_t)2048 * 512);
    k_tcvt<<<512, 256, 0, stream>>>(Uf, ut16);
    k_tcvt<<<512, 256, 0, stream>>>(Ub, ut16 + (size_t)2048 * 512);
    hipMemsetAsync(ws + o_hb, 0, (o_cnt + 256) - o_hb, stream);

    int nch = 512 / CT;
    for (int c = 0; c < nch; ++c) {
        int t0 = c * CT;
        k_proj<<<dim3(64 * CT / 128, 16, 2), 256, 0, stream>>>(x16, wt16, bf, bb, xzp, t0, CT, lct);
        const f16* a_xz = xzp; const f16* a_ut = ut16;
        f16* a_hb = hb; float* a_cb = cb; unsigned* a_cnt = cp; float* a_out = out;
        int a_t0 = t0, a_ct = CT;
        void* args[8] = {&a_xz, &a_ut, &a_hb, &a_cb, &a_cnt, &a_out, &a_t0, &a_ct};
        hipLaunchCooperativeKernel((void*)k_recur, dim3(128), dim3(256), args, 0u, stream);
    }
}

// Round 3
// 3688.285 us; speedup vs baseline: 2.7217x; 2.7217x over previous
//
#include <hip/hip_runtime.h>
#include <stdint.h>

// BiLSTM: B=64, T=512, D=512, U=512. Two independent forward-scanned LSTMs.
// Phase 0: convert inputs/weights to fp16 (weights transposed to [n][k]).
// Phase 1: xz = x @ W + b  (MFMA fp16 GEMM, per time-chunk)
// Phase 2: persistent cooperative recurrence: z = xz + h @ U, gates, h/c update.
// Sync protocol: h is published with RETURNING atomic swaps (execute at the
// coherence point; vmcnt-ack requires the returned data), drained by the
// end-of-step barrier; then a RELAXED per-WG flag store. A fire-and-forget
// sc1 store's vmcnt-ack does NOT prove coherence-point arrival (round-2 race).

typedef _Float16 f16;
typedef _Float16 f16x8 __attribute__((ext_vector_type(8)));
typedef float    f32x4 __attribute__((ext_vector_type(4)));
typedef unsigned long long u64;

typedef __attribute__((address_space(1))) const void* gas_ptr;
typedef __attribute__((address_space(3))) void* las_ptr;

__device__ inline void gl_lds16(const void* g, void* l) {
    __builtin_amdgcn_global_load_lds((gas_ptr)g, (las_ptr)l, 16, 0, 0);
}

// agent-coherent 16B load as 2 relaxed 8B atomics (bypass stale L1/L2)
__device__ inline f16x8 aload16(const f16* p) {
    union { u64 u[2]; f16x8 v; } t;
    const u64* q = (const u64*)p;
    t.u[0] = __hip_atomic_load(q + 0, __ATOMIC_RELAXED, __HIP_MEMORY_SCOPE_AGENT);
    t.u[1] = __hip_atomic_load(q + 1, __ATOMIC_RELAXED, __HIP_MEMORY_SCOPE_AGENT);
    return t.v;
}
// publish 16B via returning swaps: completion proves arrival at coherence point
__device__ inline void apub16(f16* p, f16x8 v) {
    union { u64 u[2]; f16x8 v8; } t; t.v8 = v;
    u64* q = (u64*)p;
    u64 r0 = __hip_atomic_exchange(q + 0, t.u[0], __ATOMIC_RELAXED, __HIP_MEMORY_SCOPE_AGENT);
    u64 r1 = __hip_atomic_exchange(q + 1, t.u[1], __ATOMIC_RELAXED, __HIP_MEMORY_SCOPE_AGENT);
    asm volatile("" :: "v"(r0), "v"(r1));   // keep returns live => sc0 stays => ack = MALL execution
}

// ---------------- conversion kernels ----------------

__global__ void k_cvt(const float* __restrict__ src, f16* __restrict__ dst, int n8) {
    int i = blockIdx.x * 256 + threadIdx.x;
    if (i >= n8) return;
    const float4* s = (const float4*)src;
    float4 a = s[2 * i], b = s[2 * i + 1];
    f16x8 o = {(f16)a.x, (f16)a.y, (f16)a.z, (f16)a.w,
               (f16)b.x, (f16)b.y, (f16)b.z, (f16)b.w};
    *(f16x8*)(dst + 8 * (size_t)i) = o;
}

// src [512][2048] f32 -> dst [2048][512] f16 (transpose)
__global__ void k_tcvt(const float* __restrict__ src, f16* __restrict__ dst) {
    int tid = blockIdx.x * 256 + threadIdx.x;   // 131072 total
    int kc = tid >> 11;          // 0..63  (k chunk of 8)
    int n  = tid & 2047;
    f16x8 o;
#pragma unroll
    for (int j = 0; j < 8; ++j)
        o[j] = (f16)src[(size_t)(kc * 8 + j) * 2048 + n];
    *(f16x8*)(dst + (size_t)n * 512 + kc * 8) = o;
}

// ---------------- projection GEMM ----------------
// xz[d][b][tc][n] (fp16) = x16[d][b][t0+tc][:] @ WT[d][n][:] + bias[n]

__global__ __launch_bounds__(256) void k_proj(
    const f16* __restrict__ x16, const f16* __restrict__ WT,
    const float* __restrict__ bfw, const float* __restrict__ bbw,
    f16* __restrict__ xz, int t0, int CT, int lct) {
    __shared__ f16 smem[16384];
    f16* As = smem;
    f16* Bs = smem + 8192;

    const int tid = threadIdx.x;
    const int l = tid & 63, v = tid >> 6;
    const int mt = blockIdx.x, nt = blockIdx.y, d = blockIdx.z;
    const int wm = v >> 1, wn = v & 1;
    const int lr4 = l >> 4, c16 = l & 15;

    f32x4 acc[4][4];
#pragma unroll
    for (int i = 0; i < 4; ++i)
#pragma unroll
        for (int j = 0; j < 4; ++j) acc[i][j] = (f32x4)0.f;

    auto stage = [&](int kk, int buf) {
#pragma unroll
        for (int rd = 0; rd < 2; ++rd) {
            int idx = rd * 256 + tid;
            int r = idx >> 2, kp = idx & 3;
            int m = mt * 128 + r;
            int b = m >> lct, tc = m & (CT - 1);
            const f16* ga = x16 + (((size_t)(d * 64 + b) * 512 + (t0 + tc)) * 512 + kk * 32 + kp * 8);
            gl_lds16(ga, &As[buf * 4096 + (rd * 256 + v * 64) * 8]);
        }
#pragma unroll
        for (int rd = 0; rd < 2; ++rd) {
            int idx = rd * 256 + tid;
            int r = idx >> 2, kp = idx & 3;
            const f16* gb = WT + ((size_t)(d * 2048 + nt * 128 + r) * 512 + kk * 32 + kp * 8);
            gl_lds16(gb, &Bs[buf * 4096 + (rd * 256 + v * 64) * 8]);
        }
    };

    stage(0, 0);
    for (int kk = 0; kk < 16; ++kk) {
        __syncthreads();
        if (kk < 15) stage(kk + 1, (kk + 1) & 1);
        int buf = kk & 1;
        f16x8 af[4], bfr[4];
#pragma unroll
        for (int mf = 0; mf < 4; ++mf)
            af[mf] = *(const f16x8*)&As[buf * 4096 + (wm * 64 + mf * 16 + c16) * 32 + lr4 * 8];
#pragma unroll
        for (int nf = 0; nf < 4; ++nf)
            bfr[nf] = *(const f16x8*)&Bs[buf * 4096 + (wn * 64 + nf * 16 + c16) * 32 + lr4 * 8];
#pragma unroll
        for (int mf = 0; mf < 4; ++mf)
#pragma unroll
            for (int nf = 0; nf < 4; ++nf)
                acc[mf][nf] = __builtin_amdgcn_mfma_f32_16x16x32_f16(af[mf], bfr[nf], acc[mf][nf], 0, 0, 0);
    }
    __syncthreads();

    const float* bias = d ? bbw : bfw;
    float bv[4];
#pragma unroll
    for (int nf = 0; nf < 4; ++nf) bv[nf] = bias[nt * 128 + wn * 64 + nf * 16 + c16];

    f16* Cs = smem;
#pragma unroll
    for (int mf = 0; mf < 4; ++mf)
#pragma unroll
        for (int nf = 0; nf < 4; ++nf)
#pragma unroll
            for (int r = 0; r < 4; ++r) {
                int row = wm * 64 + mf * 16 + lr4 * 4 + r;
                int col = wn * 64 + nf * 16 + c16;
                Cs[row * 128 + col] = (f16)(acc[mf][nf][r] + bv[nf]);
            }
    __syncthreads();
#pragma unroll
    for (int ch = 0; ch < 8; ++ch) {
        int flat = ch * 256 + tid;
        int row = flat >> 4, cc = flat & 15;
        int m = mt * 128 + row;
        int b = m >> lct, tc = m & (CT - 1);
        f16x8 val = *(const f16x8*)&Cs[row * 128 + cc * 8];
        *(f16x8*)&xz[((size_t)(d * 64 + b) * CT + tc) * 2048 + nt * 128 + cc * 8] = val;
    }
}

// ---------------- persistent recurrence ----------------
// 128 blocks x 256 thr: block = (dir d, batch-group grp of 16 rows, unit-WG wg).
// h stored in MFMA A-fragment layout [kb(=producer wg)][row][32 units] so the
// consumer reads each K-block as one coalesced 1KB load.

__global__ __launch_bounds__(256, 1) void k_recur(
    const f16* __restrict__ xz, const f16* __restrict__ UT,
    f16* __restrict__ hbuf, float* __restrict__ cbuf,
    unsigned* __restrict__ flags, float* __restrict__ out,
    int t0, int CT) {
    __shared__ f16 xzsm[2][2048];
    __shared__ f16 wsm[4][128];

    const int tid = threadIdx.x;
    const int l = tid & 63, v = tid >> 6;
    const int bx = blockIdx.x;
    const int d   = bx >> 6;
    const int grp = (bx >> 4) & 3;
    const int wg  = bx & 15;
    const int wu0 = wg * 32;
    const int lr4 = l >> 4;          // 0..3
    const int du  = (l & 15) >> 2;   // 0..3
    const int gid = l & 3;           // gate: 0=i 1=f 2=g 3=o
    const int gidx = d * 4 + grp;

    int unitloc[2], nstd[2];
#pragma unroll
    for (int nf = 0; nf < 2; ++nf) {
        int u = wu0 + v * 8 + nf * 4 + du;
        unitloc[nf] = v * 8 + nf * 4 + du;
        nstd[nf] = gid * 512 + u;
    }

    // resident U fragments: 2 n-frags x 16 k-frags
    f16x8 Ufr[2][16];
#pragma unroll
    for (int nf = 0; nf < 2; ++nf)
#pragma unroll
        for (int kk = 0; kk < 16; ++kk)
            Ufr[nf][kk] = *(const f16x8*)&UT[((size_t)d * 2048 + nstd[nf]) * 512 + kk * 32 + lr4 * 8];

    // c state (redundant across the 4 gate lanes)
    float cst[2][4];
#pragma unroll
    for (int nf = 0; nf < 2; ++nf)
#pragma unroll
        for (int r = 0; r < 4; ++r)
            cst[nf][r] = cbuf[((size_t)d * 64 + grp * 16 + lr4 * 4 + r) * 512 + (wu0 + v * 8 + nf * 4 + du)];

    // stage xz for tl=0
    {
        int row = tid >> 4, gate = (tid >> 2) & 3, u8 = tid & 3;
        const f16* g = xz + (((size_t)(d * 64 + grp * 16 + row) * CT + 0) * 2048 + gate * 512 + wu0 + u8 * 8);
        gl_lds16(g, &xzsm[0][v * 512]);
    }

    const size_t hstride = 16 * 16 * 32;   // one parity: 16 kb-blocks x 16 rows x 32 units
    f16* hbg = hbuf + (size_t)gidx * 2 * hstride;
    unsigned* flg = flags + gidx * 16;     // 16 dwords = one 64B line per group

    __syncthreads();   // xzsm[0] staged; Ufr/cst loads in flight (waited on use)

    for (int tl = 0; tl < CT; ++tl) {
        const int gt = t0 + tl;

        // z init from xz (LDS; prefetch was drained by the end-of-prev-step barrier)
        f32x4 acc0, acc1;
#pragma unroll
        for (int r = 0; r < 4; ++r) {
            acc0[r] = (float)xzsm[tl & 1][((lr4 * 4 + r) * 4 + gid) * 32 + unitloc[0]];
            acc1[r] = (float)xzsm[tl & 1][((lr4 * 4 + r) * 4 + gid) * 32 + unitloc[1]];
        }

        // wait for h_{gt}: poll all 16 producer flags in one wave instruction
        if (gt > 0) {
            const unsigned target = (unsigned)gt;
            while (true) {
                unsigned fv = __hip_atomic_load(flg + (l & 15), __ATOMIC_RELAXED, __HIP_MEMORY_SCOPE_AGENT);
                if (__all(fv >= target)) break;
                __builtin_amdgcn_s_sleep(2);
            }
        }
        asm volatile("" ::: "memory");

        // z += h @ U  (h in A-fragment layout: block kb at kb*512, coalesced 1KB reads)
        const f16* hsrc = hbg + (size_t)(gt & 1) * hstride + ((l & 15) * 32 + lr4 * 8);
#pragma unroll
        for (int kh = 0; kh < 2; ++kh) {
            f16x8 af[8];
#pragma unroll
            for (int j = 0; j < 8; ++j) af[j] = aload16(hsrc + (kh * 8 + j) * 512);
#pragma unroll
            for (int j = 0; j < 8; ++j) {
                acc0 = __builtin_amdgcn_mfma_f32_16x16x32_f16(af[j], Ufr[0][kh * 8 + j], acc0, 0, 0, 0);
                acc1 = __builtin_amdgcn_mfma_f32_16x16x32_f16(af[j], Ufr[1][kh * 8 + j], acc1, 0, 0, 0);
            }
        }

        // prefetch next xz now: latency hides under act/exchange/stores/barrier
        {
            int tnext = (tl + 1 < CT) ? tl + 1 : tl;   // clamped dummy on last step (unused buffer)
            int row = tid >> 4, gate = (tid >> 2) & 3, u8 = tid & 3;
            const f16* g = xz + (((size_t)(d * 64 + grp * 16 + row) * CT + tnext) * 2048 + gate * 512 + wu0 + u8 * 8);
            gl_lds16(g, &xzsm[tnext & 1][v * 512]);
        }

        // own-gate activation (gate 2 = tanh, else sigmoid)
        float act[2][4];
#pragma unroll
        for (int nf = 0; nf < 2; ++nf)
#pragma unroll
            for (int r = 0; r < 4; ++r) {
                float z = nf ? acc1[r] : acc0[r];
                float zz = (gid == 2) ? 2.f * z : z;
                float r0 = 1.f / (1.f + __expf(-zz));
                act[nf][r] = (gid == 2) ? 2.f * r0 - 1.f : r0;
            }

        // exchange gates among the 4 adjacent lanes; update c; gate0 computes h
#pragma unroll
        for (int nf = 0; nf < 2; ++nf)
#pragma unroll
            for (int r = 0; r < 4; ++r) {
                float a0 = act[nf][r];
                float a1 = __shfl_xor(a0, 1);
                float a2 = __shfl_xor(a0, 2);
                float a3 = __shfl_xor(a0, 3);
                int mi = gid, mf_ = gid ^ 1, mg = gid ^ 2, mo = gid ^ 3;
                float iv = mi == 0 ? a0 : mi == 1 ? a1 : mi == 2 ? a2 : a3;
                float fv = mf_ == 0 ? a0 : mf_ == 1 ? a1 : mf_ == 2 ? a2 : a3;
                float gv = mg == 0 ? a0 : mg == 1 ? a1 : mg == 2 ? a2 : a3;
                float ov = mo == 0 ? a0 : mo == 1 ? a1 : mo == 2 ? a2 : a3;
                float cn = fv * cst[nf][r] + iv * gv;
                cst[nf][r] = cn;
                if (gid == 0) {
                    float th = copysignf(1.f - 2.f / (__expf(2.f * fabsf(cn)) + 1.f), cn);
                    wsm[v][(nf * 4 + du) * 16 + lr4 * 4 + r] = (f16)(ov * th);
                }
            }

        // lanes 0..15 of each wave gather their batch-row; publish h (returning swaps)
        f16x8 hv8; size_t ob = 0;
        if (l < 16) {
#pragma unroll
            for (int j = 0; j < 8; ++j) hv8[j] = wsm[v][j * 16 + l];
            apub16(hbg + (size_t)((gt + 1) & 1) * hstride + ((size_t)wg * 16 + l) * 32 + v * 8, hv8);
            ob = ((size_t)(grp * 16 + l) * 512 + gt) * 1024 + d * 512 + wu0 + v * 8;
        }

        __syncthreads();   // vmcnt(0): swap returns arrived => h at coherence point; xz prefetch done

        if (tid == 0)      // relaxed is now provably ordered after the h swaps
            __hip_atomic_store(flg + wg, (unsigned)(gt + 1), __ATOMIC_RELAXED, __HIP_MEMORY_SCOPE_AGENT);

        // output stores AFTER the flag: off the critical path
        if (l < 16) {
            float4 o0 = {(float)hv8[0], (float)hv8[1], (float)hv8[2], (float)hv8[3]};
            float4 o1 = {(float)hv8[4], (float)hv8[5], (float)hv8[6], (float)hv8[7]};
            *(float4*)&out[ob] = o0;
            *(float4*)&out[ob + 4] = o1;
        }
    }

    __syncthreads();
    // persist c for next chunk
    if (gid == 0) {
#pragma unroll
        for (int nf = 0; nf < 2; ++nf)
#pragma unroll
            for (int r = 0; r < 4; ++r)
                cbuf[((size_t)d * 64 + grp * 16 + lr4 * 4 + r) * 512 + (wu0 + v * 8 + nf * 4 + du)] = cst[nf][r];
    }
}

// ---------------- host ----------------

extern "C" void kernel_launch(void* const* d_in, const int* in_sizes, int n_in,
                              void* d_out, int out_size, void* d_ws, size_t ws_size,
                              hipStream_t stream) {
    const float* xf = (const float*)d_in[0];
    const float* xb = (const float*)d_in[1];
    const float* Wf = (const float*)d_in[2];
    const float* Uf = (const float*)d_in[3];
    const float* bf = (const float*)d_in[4];
    const float* Wb = (const float*)d_in[5];
    const float* Ub = (const float*)d_in[6];
    const float* bb = (const float*)d_in[7];
    float* out = (float*)d_out;

    char* ws = (char*)d_ws;
    size_t off = 0;
    auto alloc = [&](size_t bytes) { size_t o = off; off = (off + bytes + 255) & ~(size_t)255; return o; };
    size_t o_x16 = alloc((size_t)2 * 64 * 512 * 512 * 2);
    size_t o_wt  = alloc((size_t)2 * 2048 * 512 * 2);
    size_t o_ut  = alloc((size_t)2 * 2048 * 512 * 2);
    size_t o_hb  = alloc((size_t)8 * 2 * 16 * 16 * 32 * 2);   // 8 groups x 2 parity x 16KB
    size_t o_cb  = alloc((size_t)2 * 64 * 512 * 4);
    size_t o_flg = alloc(1024);                               // 8 groups x 16 dwords (64B lines)
    size_t fixed = off;
    int CT = 512;
    while (CT > 32 && fixed + (size_t)2 * 64 * CT * 2048 * 2 > ws_size) CT >>= 1;
    size_t o_xz = alloc((size_t)2 * 64 * CT * 2048 * 2);
    int lct = (CT == 512) ? 9 : (CT == 256) ? 8 : (CT == 128) ? 7 : (CT == 64) ? 6 : 5;

    f16* x16 = (f16*)(ws + o_x16);
    f16* wt16 = (f16*)(ws + o_wt);
    f16* ut16 = (f16*)(ws + o_ut);
    f16* hb   = (f16*)(ws + o_hb);
    float* cb = (float*)(ws + o_cb);
    unsigned* fl = (unsigned*)(ws + o_flg);
    f16* xzp  = (f16*)(ws + o_xz);

    const int n8 = 16777216 / 8;   // per x tensor
    k_cvt<<<8192, 256, 0, stream>>>(xf, x16, n8);
    k_cvt<<<8192, 256, 0, stream>>>(xb, x16 + (size_t)16777216, n8);
    k_tcvt<<<512, 256, 0, stream>>>(Wf, wt16);
    k_tcvt<<<512, 256, 0, stream>>>(Wb, wt16 + (size_t)2048 * 512);
    k_tcvt<<<512, 256, 0, stream>>>(Uf, ut16);
    k_tcvt<<<512, 256, 0, stream>>>(Ub, ut16 + (size_t)2048 * 512);
    hipMemsetAsync(ws + o_hb, 0, (o_flg + 1024) - o_hb, stream);

    int nch = 512 / CT;
    for (int c = 0; c < nch; ++c) {
        int t0 = c * CT;
        k_proj<<<dim3(64 * CT / 128, 16, 2), 256, 0, stream>>>(x16, wt16, bf, bb, xzp, t0, CT, lct);
        const f16* a_xz = xzp; const f16* a_ut = ut16;
        f16* a_hb = hb; float* a_cb = cb; unsigned* a_fl = fl; float* a_out = out;
        int a_t0 = t0, a_ct = CT;
        void* args[8] = {&a_xz, &a_ut, &a_hb, &a_cb, &a_fl, &a_out, &a_t0, &a_ct};
        hipLaunchCooperativeKernel((void*)k_recur, dim3(128), dim3(256), args, 0u, stream);
    }
}

// Round 6
// 2524.890 us; speedup vs baseline: 3.9758x; 1.4608x over previous
//
#include <hip/hip_runtime.h>
#include <stdint.h>

// BiLSTM: B=64, T=512, D=512, U=512. Two independent forward-scanned LSTMs.
// Phase 0: convert inputs/weights to fp16 (weights transposed to [n][k]).
// Phase 1: xz = x @ W + b  (MFMA fp16 GEMM, per time-chunk)
// Phase 2: persistent cooperative recurrence, DATA-AS-FLAG ring buffer:
//   ring[t] = h_t, pre-filled with f16-NaN sentinel (0x7F7F bytes). Producers
//   publish via fire-and-forget 8B agent atomic stores (each granule flips
//   sentinel->data atomically; no ordering needed). Consumers poll with 8B
//   agent atomic LOADS (intrinsics -> compiler-tracked, cannot be stale),
//   each wave owns 1/4 of the tile, stages it to swizzled LDS, mid barrier,
//   all waves ds_read MFMA fragments. No inline asm, no register pinning
//   (rounds 4/5: cooperative launch silently failed with the asm/pin kernel).

typedef _Float16 f16;
typedef _Float16 f16x8 __attribute__((ext_vector_type(8)));
typedef float    f32x4 __attribute__((ext_vector_type(4)));
typedef unsigned long long u64;

typedef __attribute__((address_space(1))) const void* gas_ptr;
typedef __attribute__((address_space(3))) void* las_ptr;

__device__ inline void gl_lds16(const void* g, void* l) {
    __builtin_amdgcn_global_load_lds((gas_ptr)g, (las_ptr)l, 16, 0, 0);
}

#define SENT64 0x7F7F7F7F7F7F7F7FULL

// ---------------- conversion kernels ----------------

__global__ void k_cvt(const float* __restrict__ src, f16* __restrict__ dst, int n8) {
    int i = blockIdx.x * 256 + threadIdx.x;
    if (i >= n8) return;
    const float4* s = (const float4*)src;
    float4 a = s[2 * i], b = s[2 * i + 1];
    f16x8 o = {(f16)a.x, (f16)a.y, (f16)a.z, (f16)a.w,
               (f16)b.x, (f16)b.y, (f16)b.z, (f16)b.w};
    *(f16x8*)(dst + 8 * (size_t)i) = o;
}

// src [512][2048] f32 -> dst [2048][512] f16 (transpose)
__global__ void k_tcvt(const float* __restrict__ src, f16* __restrict__ dst) {
    int tid = blockIdx.x * 256 + threadIdx.x;   // 131072 total
    int kc = tid >> 11;
    int n  = tid & 2047;
    f16x8 o;
#pragma unroll
    for (int j = 0; j < 8; ++j)
        o[j] = (f16)src[(size_t)(kc * 8 + j) * 2048 + n];
    *(f16x8*)(dst + (size_t)n * 512 + kc * 8) = o;
}

// ---------------- ring init kernels ----------------
// Cached stores; dispatch-end release flushes dirty L2 -> visible at the
// coherence point before the next dispatch's atomic loads.

__global__ void k_fill(f16* __restrict__ ring, int CT, int zero0) {
    size_t i = ((size_t)blockIdx.x * 256 + threadIdx.x) * 8;
    const size_t slot = 65536;                    // f16 per ring slot
    size_t total = (size_t)(CT + 1) * slot;
    if (i >= total) return;
    u64 fillv = SENT64;
    if (i < slot) { if (!zero0) return; fillv = 0; }
    union { u64 u[2]; f16x8 v; } t; t.u[0] = fillv; t.u[1] = fillv;
    *(f16x8*)(ring + i) = t.v;
}

__global__ void k_copyslot(f16* __restrict__ ring, int CT) {
    size_t i = (size_t)(blockIdx.x * 256 + threadIdx.x) * 8;   // 65536 f16 total
    f16x8 v = *(const f16x8*)(ring + (size_t)CT * 65536 + i);
    *(f16x8*)(ring + i) = v;
}

// ---------------- projection GEMM ----------------
// xz[d][b][tc][n] (fp16) = x16[d][b][t0+tc][:] @ WT[d][n][:] + bias[n]

__global__ __launch_bounds__(256) void k_proj(
    const f16* __restrict__ x16, const f16* __restrict__ WT,
    const float* __restrict__ bfw, const float* __restrict__ bbw,
    f16* __restrict__ xz, int t0, int CT, int lct) {
    __shared__ f16 smem[16384];
    f16* As = smem;
    f16* Bs = smem + 8192;

    const int tid = threadIdx.x;
    const int l = tid & 63, v = tid >> 6;
    const int mt = blockIdx.x, nt = blockIdx.y, d = blockIdx.z;
    const int wm = v >> 1, wn = v & 1;
    const int lr4 = l >> 4, c16 = l & 15;

    f32x4 acc[4][4];
#pragma unroll
    for (int i = 0; i < 4; ++i)
#pragma unroll
        for (int j = 0; j < 4; ++j) acc[i][j] = (f32x4)0.f;

    auto stage = [&](int kk, int buf) {
#pragma unroll
        for (int rd = 0; rd < 2; ++rd) {
            int idx = rd * 256 + tid;
            int r = idx >> 2, kp = idx & 3;
            int m = mt * 128 + r;
            int b = m >> lct, tc = m & (CT - 1);
            const f16* ga = x16 + (((size_t)(d * 64 + b) * 512 + (t0 + tc)) * 512 + kk * 32 + kp * 8);
            gl_lds16(ga, &As[buf * 4096 + (rd * 256 + v * 64) * 8]);
        }
#pragma unroll
        for (int rd = 0; rd < 2; ++rd) {
            int idx = rd * 256 + tid;
            int r = idx >> 2, kp = idx & 3;
            const f16* gb = WT + ((size_t)(d * 2048 + nt * 128 + r) * 512 + kk * 32 + kp * 8);
            gl_lds16(gb, &Bs[buf * 4096 + (rd * 256 + v * 64) * 8]);
        }
    };

    stage(0, 0);
    for (int kk = 0; kk < 16; ++kk) {
        __syncthreads();
        if (kk < 15) stage(kk + 1, (kk + 1) & 1);
        int buf = kk & 1;
        f16x8 af[4], bfr[4];
#pragma unroll
        for (int mf = 0; mf < 4; ++mf)
            af[mf] = *(const f16x8*)&As[buf * 4096 + (wm * 64 + mf * 16 + c16) * 32 + lr4 * 8];
#pragma unroll
        for (int nf = 0; nf < 4; ++nf)
            bfr[nf] = *(const f16x8*)&Bs[buf * 4096 + (wn * 64 + nf * 16 + c16) * 32 + lr4 * 8];
#pragma unroll
        for (int mf = 0; mf < 4; ++mf)
#pragma unroll
            for (int nf = 0; nf < 4; ++nf)
                acc[mf][nf] = __builtin_amdgcn_mfma_f32_16x16x32_f16(af[mf], bfr[nf], acc[mf][nf], 0, 0, 0);
    }
    __syncthreads();

    const float* bias = d ? bbw : bfw;
    float bv[4];
#pragma unroll
    for (int nf = 0; nf < 4; ++nf) bv[nf] = bias[nt * 128 + wn * 64 + nf * 16 + c16];

    f16* Cs = smem;
#pragma unroll
    for (int mf = 0; mf < 4; ++mf)
#pragma unroll
        for (int nf = 0; nf < 4; ++nf)
#pragma unroll
            for (int r = 0; r < 4; ++r) {
                int row = wm * 64 + mf * 16 + lr4 * 4 + r;
                int col = wn * 64 + nf * 16 + c16;
                Cs[row * 128 + col] = (f16)(acc[mf][nf][r] + bv[nf]);
            }
    __syncthreads();
#pragma unroll
    for (int ch = 0; ch < 8; ++ch) {
        int flat = ch * 256 + tid;
        int row = flat >> 4, cc = flat & 15;
        int m = mt * 128 + row;
        int b = m >> lct, tc = m & (CT - 1);
        f16x8 val = *(const f16x8*)&Cs[row * 128 + cc * 8];
        *(f16x8*)&xz[((size_t)(d * 64 + b) * CT + tc) * 2048 + nt * 128 + cc * 8] = val;
    }
}

// ---------------- persistent recurrence ----------------
// 128 blocks x 256 thr: block = (dir d, batch-group grp of 16 rows, unit-WG wg).
// ring slot layout: [group gidx][kb 0..15][row 0..15][32 units] f16.
// Wave v polls+stages kb 4v..4v+3 into hsm (XOR-swizzled); all waves read all kb.

__global__ __launch_bounds__(256, 1) void k_recur(
    const f16* __restrict__ xz, const f16* __restrict__ UT,
    f16* __restrict__ ring, float* __restrict__ cbuf,
    float* __restrict__ out, int t0, int CT) {
    __shared__ f16 xzsm[2][2048];
    __shared__ f16 wsm[4][128];
    __shared__ f16 hsm[8192];      // 16KB: [kb][row][32], 16B slots XOR-swizzled by (row&7)<<4

    const int tid = threadIdx.x;
    const int l = tid & 63, v = tid >> 6;
    const int bx = blockIdx.x;
    const int d   = bx >> 6;
    const int grp = (bx >> 4) & 3;
    const int wg  = bx & 15;
    const int wu0 = wg * 32;
    const int lr4 = l >> 4;          // 0..3
    const int du  = (l & 15) >> 2;   // 0..3
    const int gid = l & 3;           // gate: 0=i 1=f 2=g 3=o
    const int gidx = d * 4 + grp;

    int unitloc[2], nstd[2];
#pragma unroll
    for (int nf = 0; nf < 2; ++nf) {
        int u = wu0 + v * 8 + nf * 4 + du;
        unitloc[nf] = v * 8 + nf * 4 + du;
        nstd[nf] = gid * 512 + u;
    }

    // resident U fragments: 2 n-frags x 16 k-frags (compiler-managed)
    f16x8 Ufr[2][16];
#pragma unroll
    for (int nf = 0; nf < 2; ++nf)
#pragma unroll
        for (int kk = 0; kk < 16; ++kk)
            Ufr[nf][kk] = *(const f16x8*)&UT[((size_t)d * 2048 + nstd[nf]) * 512 + kk * 32 + lr4 * 8];

    // c state (redundant across the 4 gate lanes)
    float cst[2][4];
#pragma unroll
    for (int nf = 0; nf < 2; ++nf)
#pragma unroll
        for (int r = 0; r < 4; ++r)
            cst[nf][r] = cbuf[((size_t)d * 64 + grp * 16 + lr4 * 4 + r) * 512 + (wu0 + v * 8 + nf * 4 + du)];

    // stage xz for tl=0
    {
        int row = tid >> 4, gate = (tid >> 2) & 3, u8 = tid & 3;
        const f16* g = xz + (((size_t)(d * 64 + grp * 16 + row) * CT + 0) * 2048 + gate * 512 + wu0 + u8 * 8);
        gl_lds16(g, &xzsm[0][v * 512]);
    }

    __syncthreads();   // xzsm[0] staged

    for (int tl = 0; tl < CT; ++tl) {
        const int gt = t0 + tl;

        // z init from xz (LDS; staged by prev step's mid barrier)
        f32x4 acc0, acc1;
#pragma unroll
        for (int r = 0; r < 4; ++r) {
            acc0[r] = (float)xzsm[tl & 1][((lr4 * 4 + r) * 4 + gid) * 32 + unitloc[0]];
            acc1[r] = (float)xzsm[tl & 1][((lr4 * 4 + r) * 4 + gid) * 32 + unitloc[1]];
        }

        // prefetch next xz early (completes by this step's mid barrier)
        {
            int tnext = (tl + 1 < CT) ? tl + 1 : tl;
            int row = tid >> 4, gate = (tid >> 2) & 3, u8 = tid & 3;
            const f16* g = xz + (((size_t)(d * 64 + grp * 16 + row) * CT + tnext) * 2048 + gate * 512 + wu0 + u8 * 8);
            gl_lds16(g, &xzsm[tnext & 1][v * 512]);
        }

        // data-as-flag poll: wave v owns kb 4v..4v+3; lane covers 16B of each kb.
        // 8B atomic loads (agent scope -> coherence point); granule is sentinel
        // or final data (producer stores are 8B atomics).
        const u64* sbase = (const u64*)ring + (size_t)tl * 16384 + (size_t)gidx * 2048
                         + (size_t)(v * 4) * 128 + l * 2;
        u64 g0, g1, g2, g3, g4, g5, g6, g7;
        while (true) {
            g0 = __hip_atomic_load(sbase +   0, __ATOMIC_RELAXED, __HIP_MEMORY_SCOPE_AGENT);
            g1 = __hip_atomic_load(sbase +   1, __ATOMIC_RELAXED, __HIP_MEMORY_SCOPE_AGENT);
            g2 = __hip_atomic_load(sbase + 128, __ATOMIC_RELAXED, __HIP_MEMORY_SCOPE_AGENT);
            g3 = __hip_atomic_load(sbase + 129, __ATOMIC_RELAXED, __HIP_MEMORY_SCOPE_AGENT);
            g4 = __hip_atomic_load(sbase + 256, __ATOMIC_RELAXED, __HIP_MEMORY_SCOPE_AGENT);
            g5 = __hip_atomic_load(sbase + 257, __ATOMIC_RELAXED, __HIP_MEMORY_SCOPE_AGENT);
            g6 = __hip_atomic_load(sbase + 384, __ATOMIC_RELAXED, __HIP_MEMORY_SCOPE_AGENT);
            g7 = __hip_atomic_load(sbase + 385, __ATOMIC_RELAXED, __HIP_MEMORY_SCOPE_AGENT);
            unsigned bad = (g0 == SENT64) | (g1 == SENT64) | (g2 == SENT64) | (g3 == SENT64)
                         | (g4 == SENT64) | (g5 == SENT64) | (g6 == SENT64) | (g7 == SENT64);
            if (!__any(bad)) break;
            __builtin_amdgcn_s_sleep(1);
        }

        // stage own quarter into LDS (swizzled 16B slots)
        {
            u64 gg[4][2] = {{g0, g1}, {g2, g3}, {g4, g5}, {g6, g7}};
#pragma unroll
            for (int jj = 0; jj < 4; ++jj) {
                union { u64 u[2]; f16x8 v8; } t; t.u[0] = gg[jj][0]; t.u[1] = gg[jj][1];
                int byte = (v * 4 + jj) * 1024 + l * 16;
                byte ^= ((l >> 2) & 7) << 4;
                *(f16x8*)((char*)hsm + byte) = t.v8;
            }
        }
        __syncthreads();   // h tile staged; xz prefetch drained

        // z += h @ U  (fragments from LDS, bank-spread by swizzle)
#pragma unroll
        for (int j = 0; j < 16; ++j) {
            int byte = j * 1024 + (l & 15) * 64 + lr4 * 16;
            byte ^= (l & 7) << 4;
            f16x8 a = *(const f16x8*)((const char*)hsm + byte);
            acc0 = __builtin_amdgcn_mfma_f32_16x16x32_f16(a, Ufr[0][j], acc0, 0, 0, 0);
            acc1 = __builtin_amdgcn_mfma_f32_16x16x32_f16(a, Ufr[1][j], acc1, 0, 0, 0);
        }

        // own-gate activation (gate 2 = tanh, else sigmoid)
        float act[2][4];
#pragma unroll
        for (int nf = 0; nf < 2; ++nf)
#pragma unroll
            for (int r = 0; r < 4; ++r) {
                float z = nf ? acc1[r] : acc0[r];
                float zz = (gid == 2) ? 2.f * z : z;
                float r0 = 1.f / (1.f + __expf(-zz));
                act[nf][r] = (gid == 2) ? 2.f * r0 - 1.f : r0;
            }

        // exchange gates among the 4 adjacent lanes; update c; gate0 computes h
#pragma unroll
        for (int nf = 0; nf < 2; ++nf)
#pragma unroll
            for (int r = 0; r < 4; ++r) {
                float a0 = act[nf][r];
                float a1 = __shfl_xor(a0, 1);
                float a2 = __shfl_xor(a0, 2);
                float a3 = __shfl_xor(a0, 3);
                int mi = gid, mf_ = gid ^ 1, mg = gid ^ 2, mo = gid ^ 3;
                float iv = mi == 0 ? a0 : mi == 1 ? a1 : mi == 2 ? a2 : a3;
                float fv = mf_ == 0 ? a0 : mf_ == 1 ? a1 : mf_ == 2 ? a2 : a3;
                float gv = mg == 0 ? a0 : mg == 1 ? a1 : mg == 2 ? a2 : a3;
                float ov = mo == 0 ? a0 : mo == 1 ? a1 : mo == 2 ? a2 : a3;
                float cn = fv * cst[nf][r] + iv * gv;
                cst[nf][r] = cn;
                if (gid == 0) {
                    float th = copysignf(1.f - 2.f / (__expf(2.f * fabsf(cn)) + 1.f), cn);
                    wsm[v][(nf * 4 + du) * 16 + lr4 * 4 + r] = (f16)(ov * th);
                }
            }

        // lanes 0..15 gather their batch-row; publish h (fire-and-forget 8B atomics)
        if (l < 16) {
            f16x8 hv8;
#pragma unroll
            for (int j = 0; j < 8; ++j) hv8[j] = wsm[v][j * 16 + l];
            f16* dst = ring + (size_t)(tl + 1) * 65536 + (size_t)gidx * 8192
                     + ((size_t)wg * 16 + l) * 32 + v * 8;
            union { u64 u[2]; f16x8 v8; } t; t.v8 = hv8;
            __hip_atomic_store((u64*)dst + 0, t.u[0], __ATOMIC_RELAXED, __HIP_MEMORY_SCOPE_AGENT);
            __hip_atomic_store((u64*)dst + 1, t.u[1], __ATOMIC_RELAXED, __HIP_MEMORY_SCOPE_AGENT);
            size_t ob = ((size_t)(grp * 16 + l) * 512 + gt) * 1024 + d * 512 + wu0 + v * 8;
            float4 o0 = {(float)hv8[0], (float)hv8[1], (float)hv8[2], (float)hv8[3]};
            float4 o1 = {(float)hv8[4], (float)hv8[5], (float)hv8[6], (float)hv8[7]};
            *(float4*)&out[ob] = o0;
            *(float4*)&out[ob + 4] = o1;
        }

        __syncthreads();   // wsm/hsm reuse + xzsm parity hand-off
    }

    // persist c for next chunk
    if (gid == 0) {
#pragma unroll
        for (int nf = 0; nf < 2; ++nf)
#pragma unroll
            for (int r = 0; r < 4; ++r)
                cbuf[((size_t)d * 64 + grp * 16 + lr4 * 4 + r) * 512 + (wu0 + v * 8 + nf * 4 + du)] = cst[nf][r];
    }
}

// ---------------- host ----------------

extern "C" void kernel_launch(void* const* d_in, const int* in_sizes, int n_in,
                              void* d_out, int out_size, void* d_ws, size_t ws_size,
                              hipStream_t stream) {
    const float* xf = (const float*)d_in[0];
    const float* xb = (const float*)d_in[1];
    const float* Wf = (const float*)d_in[2];
    const float* Uf = (const float*)d_in[3];
    const float* bf = (const float*)d_in[4];
    const float* Wb = (const float*)d_in[5];
    const float* Ub = (const float*)d_in[6];
    const float* bb = (const float*)d_in[7];
    float* out = (float*)d_out;

    char* ws = (char*)d_ws;
    size_t off = 0;
    auto alloc = [&](size_t bytes) { size_t o = off; off = (off + bytes + 255) & ~(size_t)255; return o; };
    size_t o_x16 = alloc((size_t)2 * 64 * 512 * 512 * 2);
    size_t o_wt  = alloc((size_t)2 * 2048 * 512 * 2);
    size_t o_ut  = alloc((size_t)2 * 2048 * 512 * 2);
    size_t o_cb  = alloc((size_t)2 * 64 * 512 * 4);
    size_t fixed = off;
    int CT = 512;
    while (CT > 32 && fixed + (size_t)(CT + 1) * 131072 + (size_t)2 * 64 * CT * 2048 * 2 > ws_size) CT >>= 1;
    size_t o_ring = alloc((size_t)(CT + 1) * 131072);
    size_t o_xz   = alloc((size_t)2 * 64 * CT * 2048 * 2);
    int lct = (CT == 512) ? 9 : (CT == 256) ? 8 : (CT == 128) ? 7 : (CT == 64) ? 6 : 5;

    f16* x16 = (f16*)(ws + o_x16);
    f16* wt16 = (f16*)(ws + o_wt);
    f16* ut16 = (f16*)(ws + o_ut);
    float* cb = (float*)(ws + o_cb);
    f16* ring = (f16*)(ws + o_ring);
    f16* xzp  = (f16*)(ws + o_xz);

    const int n8 = 16777216 / 8;   // per x tensor
    k_cvt<<<8192, 256, 0, stream>>>(xf, x16, n8);
    k_cvt<<<8192, 256, 0, stream>>>(xb, x16 + (size_t)16777216, n8);
    k_tcvt<<<512, 256, 0, stream>>>(Wf, wt16);
    k_tcvt<<<512, 256, 0, stream>>>(Wb, wt16 + (size_t)2048 * 512);
    k_tcvt<<<512, 256, 0, stream>>>(Uf, ut16);
    k_tcvt<<<512, 256, 0, stream>>>(Ub, ut16 + (size_t)2048 * 512);
    hipMemsetAsync(cb, 0, (size_t)2 * 64 * 512 * 4, stream);

    int nch = 512 / CT;
    int fillgrid = (int)(((size_t)(CT + 1) * 65536 / 8 + 255) / 256);
    for (int c = 0; c < nch; ++c) {
        int t0 = c * CT;
        k_proj<<<dim3(64 * CT / 128, 16, 2), 256, 0, stream>>>(x16, wt16, bf, bb, xzp, t0, CT, lct);
        if (c > 0) k_copyslot<<<32, 256, 0, stream>>>(ring, CT);
        k_fill<<<fillgrid, 256, 0, stream>>>(ring, CT, c == 0 ? 1 : 0);
        const f16* a_xz = xzp; const f16* a_ut = ut16;
        f16* a_ring = ring; float* a_cb = cb; float* a_out = out;
        int a_t0 = t0, a_ct = CT;
        void* args[7] = {&a_xz, &a_ut, &a_ring, &a_cb, &a_out, &a_t0, &a_ct};
        hipLaunchCooperativeKernel((void*)k_recur, dim3(128), dim3(256), args, 0u, stream);
    }
}